// Round 11
// baseline (498.719 us; speedup 1.0000x reference)
//
#include <hip/hip_runtime.h>
#include <hip/hip_bf16.h>

typedef unsigned short u16;
typedef unsigned int u32;
typedef short bf16x8 __attribute__((ext_vector_type(8)));
typedef float f32x4 __attribute__((ext_vector_type(4)));

#define NB 128
#define SN 576
#define DD 768
#define RR 192
#define NE 8

// output offsets (floats)
#define O1 56623104   // router_logits [128,8]
#define O2 56624128   // selected [128,1] (as float)
#define O3 56624256   // expert_weights [128,8]
#define O4 56625280   // importance [8]
#define O5 56625288   // load [8]

__device__ __forceinline__ u16 f2bf(float x) {
  union { float f; unsigned u; } v; v.f = x;
  unsigned r = v.u + 0x7fffu + ((v.u >> 16) & 1u);
  return (u16)(r >> 16);
}

__device__ __forceinline__ void gload16(const u16* g, u16* l) {
  __builtin_amdgcn_global_load_lds((const __attribute__((address_space(1))) void*)g,
                                   (__attribute__((address_space(3))) void*)l, 16, 0, 0);
}

// ---------------- kernel 0: zero control state (each call -> replay-deterministic) -------
__global__ void zero_kernel(int* __restrict__ qhead, int* __restrict__ transCnt,
                            int* __restrict__ cnt, int* __restrict__ flag,
                            float* __restrict__ out) {
  int t = threadIdx.x;
  if (t == 0) { *qhead = 0; *transCnt = 0; }
  if (t < 128) { cnt[t] = 0; flag[t] = 0; }
  if (t < 16) out[O4 + t] = 0.f;
}

// ---------------- mega kernel: work queue {pool | transpose | gate | adapter} ------------
// items 0..767: pool slab (sample c/6, rows 96*(c%6)..+96), tokens->bf16 + partials
//               6th finisher per sample computes gate inline, publishes flag[b]
// items 768..1343: W1/W2 transposes (R5 bodies)
// items 1344..2111: adapter tile (sample a/6, tile a%6) — spins on flag[b] & transCnt
__launch_bounds__(256, 2)
__global__ void mega_kernel(const float* __restrict__ tok, const float* __restrict__ Wg,
                            const float* __restrict__ bg, const float* __restrict__ W1,
                            const float* __restrict__ W2, const float* __restrict__ b1,
                            const float* __restrict__ b2, u16* __restrict__ tokbf,
                            float* __restrict__ partials, u16* __restrict__ W1T,
                            u16* __restrict__ W2T, int* __restrict__ qhead,
                            int* __restrict__ transCnt, int* __restrict__ cnt,
                            int* __restrict__ flag, int* __restrict__ eArr,
                            float* __restrict__ pArr, float* __restrict__ out) {
  __shared__ __align__(16) unsigned char smem[73728];
  __shared__ int claimS, gFlag;
  int t = threadIdx.x;
  int myItem = -1;

  for (;;) {
    if (t == 0) claimS = atomicAdd(qhead, 1);
    __syncthreads();
    int c = claimS;
    __syncthreads();
    if (c >= 1344) { myItem = c - 1344; break; }

    if (c < 768) {
      // ---- pool slab (R5 body) ----
      int s = c / 6, slab = c % 6;
      int r0 = slab * 96;
      const float* p = tok + (size_t)s * SN * DD + (size_t)r0 * DD;
      u16* q = tokbf + (size_t)s * SN * DD + (size_t)r0 * DD;
      float a0 = 0.f, a1 = 0.f, a2 = 0.f;
#pragma unroll 4
      for (int n = 0; n < 96; ++n) {
        size_t ro = (size_t)n * DD;
        float v0 = p[ro + t];
        float v1 = p[ro + t + 256];
        float v2 = p[ro + t + 512];
        a0 += v0; a1 += v1; a2 += v2;
        q[ro + t] = f2bf(v0);
        q[ro + t + 256] = f2bf(v1);
        q[ro + t + 512] = f2bf(v2);
      }
      float* pp = partials + (size_t)slab * NB * DD + (size_t)s * DD;
      pp[t] = a0; pp[t + 256] = a1; pp[t + 512] = a2;
      __threadfence();
      if (t == 0) {
        int prev = __hip_atomic_fetch_add(&cnt[s], 1, __ATOMIC_RELEASE, __HIP_MEMORY_SCOPE_AGENT);
        gFlag = (prev == 5) ? 1 : 0;
      }
      __syncthreads();
      if (gFlag) {
        // ---- gate for sample s (whole block) ----
        __builtin_amdgcn_fence(__ATOMIC_ACQUIRE, "agent");  // fresh partials (cross-XCD)
        float acc[NE];
#pragma unroll
        for (int e2 = 0; e2 < NE; ++e2) acc[e2] = 0.f;
        for (int d = t; d < DD; d += 256) {
          float x = 0.f;
#pragma unroll
          for (int k = 0; k < 6; ++k) x += partials[(size_t)k * NB * DD + (size_t)s * DD + d];
          x *= (1.0f / 576.0f);
          const float* wrow = Wg + d * NE;
#pragma unroll
          for (int e2 = 0; e2 < NE; ++e2) acc[e2] += x * wrow[e2];
        }
#pragma unroll
        for (int off = 32; off > 0; off >>= 1) {
#pragma unroll
          for (int e2 = 0; e2 < NE; ++e2) acc[e2] += __shfl_down(acc[e2], off);
        }
        float* red = (float*)smem;   // 4 waves x 8
        if ((t & 63) == 0) {
#pragma unroll
          for (int e2 = 0; e2 < NE; ++e2) red[(t >> 6) * NE + e2] = acc[e2];
        }
        __syncthreads();
        if (t == 0) {
          float lg[NE];
#pragma unroll
          for (int e2 = 0; e2 < NE; ++e2)
            lg[e2] = red[e2] + red[NE + e2] + red[2 * NE + e2] + red[3 * NE + e2] + bg[e2];
#pragma unroll
          for (int e2 = 0; e2 < NE; ++e2) out[O1 + s * NE + e2] = lg[e2];
          float m = lg[0]; int bi = 0;
#pragma unroll
          for (int e2 = 1; e2 < NE; ++e2) { if (lg[e2] > m) { m = lg[e2]; bi = e2; } }
          float sum = 0.f;
#pragma unroll
          for (int e2 = 0; e2 < NE; ++e2) sum += expf(lg[e2] - m);
          float pv = 1.0f / sum;
          out[O2 + s] = (float)bi;
#pragma unroll
          for (int e2 = 0; e2 < NE; ++e2) out[O3 + s * NE + e2] = (e2 == bi) ? pv : 0.f;
          atomicAdd(&out[O4 + bi], pv);
          atomicAdd(&out[O5 + bi], 1.0f / 128.0f);
          eArr[s] = bi;
          pArr[s] = pv;
          __threadfence();
          __hip_atomic_store(&flag[s], 1, __ATOMIC_RELEASE, __HIP_MEMORY_SCOPE_AGENT);
        }
        __syncthreads();
      }
    } else {
      // ---- weight transpose (R5 body) ----
      float (*tile)[65] = (float(*)[65])smem;
      int c2 = c - 768;
      const float* src; u16* dst;
      int srcld, dstld, row_off, col_off, wrow_off, wcol_off;
      if (c2 < 288) {
        int e2 = c2 / 36, rem = c2 % 36;
        int dt = rem / 3, rt = rem % 3;
        src = W1 + (size_t)e2 * DD * RR; srcld = RR;
        dst = W1T + (size_t)e2 * RR * DD; dstld = DD;
        row_off = dt * 64; col_off = rt * 64;
        wrow_off = rt * 64; wcol_off = dt * 64;
      } else {
        int i = c2 - 288;
        int e2 = i / 36, rem = i % 36;
        int rt = rem / 12, dt = rem % 12;
        src = W2 + (size_t)e2 * RR * DD; srcld = DD;
        dst = W2T + (size_t)e2 * DD * RR; dstld = RR;
        row_off = rt * 64; col_off = dt * 64;
        wrow_off = dt * 64; wcol_off = rt * 64;
      }
#pragma unroll
      for (int it = 0; it < 16; ++it) {
        int idx = t + 256 * it;
        int r = idx >> 6, cc = idx & 63;
        tile[r][cc] = src[(size_t)(row_off + r) * srcld + col_off + cc];
      }
      __syncthreads();
#pragma unroll
      for (int it = 0; it < 8; ++it) {
        int idx = t + 256 * it;
        int r2 = idx >> 5, cp = idx & 31;
        u32 pack = (u32)f2bf(tile[2 * cp][r2]) | ((u32)f2bf(tile[2 * cp + 1][r2]) << 16);
        *(u32*)&dst[(size_t)(wrow_off + r2) * dstld + wcol_off + 2 * cp] = pack;
      }
      __threadfence();
      if (t == 0)
        __hip_atomic_fetch_add(transCnt, 1, __ATOMIC_RELEASE, __HIP_MEMORY_SCOPE_AGENT);
      __syncthreads();
    }
  }

  if (myItem >= 768) return;   // surplus claims

  // =================== adapter tile (R5-proven core, verbatim) ===================
  int b = myItem / 6, tile6 = myItem % 6;
  int row0 = tile6 * 96;
  // wait for gate + transposes, then acquire (L2 invalidate for cross-XCD data)
  if (t == 0) {
    while (__hip_atomic_load(&flag[b], __ATOMIC_RELAXED, __HIP_MEMORY_SCOPE_AGENT) == 0 ||
           __hip_atomic_load(transCnt, __ATOMIC_RELAXED, __HIP_MEMORY_SCOPE_AGENT) < 576)
      __builtin_amdgcn_s_sleep(2);
  }
  __syncthreads();
  __builtin_amdgcn_fence(__ATOMIC_ACQUIRE, "agent");

  int l = t & 63;
  int w = t >> 6;
  int wr = w >> 1;
  int wc = w & 1;
  int lr = l & 15;
  int kg = l >> 4;

  int e = eArr[b];
  float p = pArr[b];

  const u16* Xg = tokbf + (size_t)b * SN * DD + (size_t)row0 * DD;
  const u16* W1g = W1T + (size_t)e * RR * DD;
  const u16* W2g = W2T + (size_t)e * DD * RR;

  auto stage1 = [&](int kt, int buf) {
    u16* Xs = (u16*)(smem + buf * 12288);
    u16* Ws = (u16*)(smem + 24576 + buf * 24576);
    int kb = kt * 64;
#pragma unroll
    for (int i = 0; i < 3; ++i) {
      int idx = t + 256 * i;          // 0..767
      int row = idx >> 3, g = idx & 7;
      gload16(Xg + (size_t)row * DD + kb + ((g ^ (row & 7)) << 3), Xs + idx * 8);
    }
#pragma unroll
    for (int i = 0; i < 6; ++i) {
      int idx = t + 256 * i;          // 0..1535
      int r = idx >> 3, g = idx & 7;
      gload16(W1g + (size_t)r * DD + kb + ((g ^ (r & 7)) << 3), Ws + idx * 8);
    }
  };

  f32x4 acc1[3][6];
#pragma unroll
  for (int i = 0; i < 3; ++i)
#pragma unroll
    for (int j = 0; j < 6; ++j) acc1[i][j] = (f32x4){0.f, 0.f, 0.f, 0.f};

  // ---- phase 1: 12 K-steps BK=64, dbuf, 1-ahead, counted vmcnt ----
  stage1(0, 0);
  int cur = 0;
  for (int kt = 0; kt < 12; ++kt) {
    if (kt < 11) {
      stage1(kt + 1, cur ^ 1);
      asm volatile("s_waitcnt vmcnt(9)" ::: "memory");
    } else {
      asm volatile("s_waitcnt vmcnt(0)" ::: "memory");
    }
    __builtin_amdgcn_s_barrier();
    u16* Xs = (u16*)(smem + cur * 12288);
    u16* Ws = (u16*)(smem + 24576 + cur * 24576);
#pragma unroll
    for (int ks = 0; ks < 2; ++ks) {
      int q = ks * 4 + kg;
      bf16x8 a[3], bb[6];
#pragma unroll
      for (int i = 0; i < 3; ++i) {
        int row = wr * 48 + i * 16 + lr;
        a[i] = *(const bf16x8*)&Xs[row * 64 + ((q ^ (row & 7)) << 3)];
      }
#pragma unroll
      for (int j = 0; j < 6; ++j) {
        int cc = wc * 96 + j * 16 + lr;
        bb[j] = *(const bf16x8*)&Ws[cc * 64 + ((q ^ (cc & 7)) << 3)];
      }
#pragma unroll
      for (int i = 0; i < 3; ++i)
#pragma unroll
        for (int j = 0; j < 6; ++j)
          acc1[i][j] = __builtin_amdgcn_mfma_f32_16x16x32_bf16(a[i], bb[j], acc1[i][j], 0, 0, 0);
    }
    asm volatile("" ::: "memory");
    __builtin_amdgcn_s_barrier();
    cur ^= 1;
  }

  auto stage2 = [&](int nc, int kt2, int buf) {
    u16* Wb = (u16*)(smem + 36864 + buf * 16384);
#pragma unroll
    for (int i = 0; i < 4; ++i) {
      int idx = t + 256 * i;          // 0..1023
      int cc = idx >> 3, g = idx & 7;
      gload16(W2g + (size_t)(nc * 128 + cc) * RR + kt2 * 64 + ((g ^ (cc & 7)) << 3), Wb + idx * 8);
    }
  };
  stage2(0, 0, 0);  // lands during gelu epilogue

  // ---- epilogue 1: bias + gelu -> Hs (bf16, granule-swizzled, ld=192) ----
  u16* Hs = (u16*)smem;
#pragma unroll
  for (int j = 0; j < 6; ++j) {
    int col = wc * 96 + j * 16 + lr;
    float bv = b1[e * RR + col];
#pragma unroll
    for (int i = 0; i < 3; ++i) {
      int rbase = wr * 48 + i * 16 + kg * 4;
#pragma unroll
      for (int r2 = 0; r2 < 4; ++r2) {
        int row = rbase + r2;
        float x = acc1[i][j][r2] + bv;
        float x3 = x * (1.f + 0.044715f * x * x);
        float tt = 0.7978845608028654f * x3;
        float ex = __expf(2.f * tt);
        float th = 1.f - 2.f / (ex + 1.f);
        float h = 0.5f * x * (1.f + th);
        Hs[row * 192 + ((((col >> 3) ^ (row & 7)) << 3) | (col & 7))] = f2bf(h);
      }
    }
  }
  __syncthreads();

  // ---- phase 2: 6 chunks x 3 K-steps, W2 dbuf, counted vmcnt (stores in flight) ----
  for (int nc = 0; nc < 6; ++nc) {
    f32x4 acc2[3][4];
#pragma unroll
    for (int i = 0; i < 3; ++i)
#pragma unroll
      for (int j = 0; j < 4; ++j) acc2[i][j] = (f32x4){0.f, 0.f, 0.f, 0.f};

    for (int kt2 = 0; kt2 < 3; ++kt2) {
      int s = nc * 3 + kt2;
      if (s < 17) {
        int nc2 = (kt2 == 2) ? nc + 1 : nc;
        int kt2b = (kt2 == 2) ? 0 : kt2 + 1;
        stage2(nc2, kt2b, (s + 1) & 1);
      }
      if (s == 17)
        asm volatile("s_waitcnt vmcnt(0)" ::: "memory");
      else if (kt2 == 0 && s > 0)
        asm volatile("s_waitcnt vmcnt(52)" ::: "memory");
      else
        asm volatile("s_waitcnt vmcnt(4)" ::: "memory");
      __builtin_amdgcn_s_barrier();

      u16* Wb = (u16*)(smem + 36864 + (s & 1) * 16384);
#pragma unroll
      for (int ks = 0; ks < 2; ++ks) {
        int q2 = ks * 4 + kg;
        int q = kt2 * 8 + q2;
        bf16x8 a[3], bb[4];
#pragma unroll
        for (int i = 0; i < 3; ++i) {
          int row = wr * 48 + i * 16 + lr;
          a[i] = *(const bf16x8*)&Hs[row * 192 + ((q ^ (row & 7)) << 3)];
        }
#pragma unroll
        for (int j = 0; j < 4; ++j) {
          int cc = wc * 64 + j * 16 + lr;
          bb[j] = *(const bf16x8*)&Wb[cc * 64 + ((q2 ^ (cc & 7)) << 3)];
        }
#pragma unroll
        for (int i = 0; i < 3; ++i)
#pragma unroll
          for (int j = 0; j < 4; ++j)
            acc2[i][j] = __builtin_amdgcn_mfma_f32_16x16x32_bf16(a[i], bb[j], acc2[i][j], 0, 0, 0);
      }
      if (kt2 == 2) {
#pragma unroll
        for (int j = 0; j < 4; ++j) {
          int colg = nc * 128 + wc * 64 + j * 16 + lr;
          float bv = b2[e * DD + colg];
#pragma unroll
          for (int i = 0; i < 3; ++i) {
            int rbase = row0 + wr * 48 + i * 16 + kg * 4;
#pragma unroll
            for (int r2 = 0; r2 < 4; ++r2) {
              out[(size_t)b * SN * DD + (size_t)(rbase + r2) * DD + colg] = p * (acc2[i][j][r2] + bv);
            }
          }
        }
      }
      asm volatile("" ::: "memory");
      __builtin_amdgcn_s_barrier();
    }
  }
}

extern "C" void kernel_launch(void* const* d_in, const int* in_sizes, int n_in,
                              void* d_out, int out_size, void* d_ws, size_t ws_size,
                              hipStream_t stream) {
  (void)in_sizes; (void)n_in; (void)out_size; (void)ws_size;
  const float* tok = (const float*)d_in[0];
  const float* Wg  = (const float*)d_in[1];
  const float* bg  = (const float*)d_in[2];
  const float* W1  = (const float*)d_in[3];
  const float* b1  = (const float*)d_in[4];
  const float* W2  = (const float*)d_in[5];
  const float* b2  = (const float*)d_in[6];
  float* out = (float*)d_out;

  char* w = (char*)d_ws;
  u16*  tokbf    = (u16*)w;                      // 113,246,208 B
  float* partials = (float*)(w + 113246208);     // 2,359,296 B
  u16*  W1T      = (u16*)(w + 115605504);        // 2,359,296 B
  u16*  W2T      = (u16*)(w + 117964800);        // 2,359,296 B
  int*  qhead    = (int*)(w + 120324096);        // 4 B
  int*  transCnt = (int*)(w + 120324160);        // 4 B
  int*  cnt      = (int*)(w + 120324224);        // 512 B
  int*  flag     = (int*)(w + 120324736);        // 512 B
  int*  eArr     = (int*)(w + 120325248);        // 512 B
  float* pArr    = (float*)(w + 120325760);      // 512 B

  hipLaunchKernelGGL(zero_kernel, dim3(1), dim3(256), 0, stream, qhead, transCnt, cnt, flag, out);
  hipLaunchKernelGGL(mega_kernel, dim3(768), dim3(256), 0, stream,
                     tok, Wg, bg, W1, W2, b1, b2, tokbf, partials, W1T, W2T,
                     qhead, transCnt, cnt, flag, eArr, pArr, out);
}

// Round 12
// 187.957 us; speedup vs baseline: 2.6534x; 2.6534x over previous
//
#include <hip/hip_runtime.h>
#include <hip/hip_bf16.h>

typedef unsigned short u16;
typedef unsigned int u32;
typedef short bf16x8 __attribute__((ext_vector_type(8)));
typedef float f32x4 __attribute__((ext_vector_type(4)));

#define NB 128
#define SN 576
#define DD 768
#define RR 192
#define NE 8

// output offsets (floats)
#define O1 56623104   // router_logits [128,8]
#define O2 56624128   // selected [128,1] (as float)
#define O3 56624256   // expert_weights [128,8]
#define O4 56625280   // importance [8]
#define O5 56625288   // load [8]

__device__ __forceinline__ u16 f2bf(float x) {
  union { float f; unsigned u; } v; v.f = x;
  unsigned r = v.u + 0x7fffu + ((v.u >> 16) & 1u);
  return (u16)(r >> 16);
}

__device__ __forceinline__ void gload16(const u16* g, u16* l) {
  __builtin_amdgcn_global_load_lds((const __attribute__((address_space(1))) void*)g,
                                   (__attribute__((address_space(3))) void*)l, 16, 0, 0);
}

// ---------------- kernel 1: prep ----------------
// blocks 0..767   : pooling slabs (sample s = blk/6, rows [96*(blk%6), +96)) + tokens->bf16
//                   -> partials[slab][s][col] (summed by gate; no atomics, deterministic)
// blocks 768..1055: W1 [e][768][192] -> W1T [e][192][768] bf16 (64x64 LDS tiles)
// blocks 1056..1343: W2 [e][192][768] -> W2T [e][768][192] bf16
__global__ void prep_kernel(const float* __restrict__ tok, u16* __restrict__ tokbf,
                            float* __restrict__ partials,
                            const float* __restrict__ W1, const float* __restrict__ W2,
                            u16* __restrict__ W1T, u16* __restrict__ W2T,
                            float* __restrict__ out) {
  __shared__ float tile[64][65];
  int blk = blockIdx.x, t = threadIdx.x;
  if (blk < 768) {
    int s = blk / 6, slab = blk % 6;
    int r0 = slab * 96;
    const float* p = tok + (size_t)s * SN * DD + (size_t)r0 * DD;
    u16* q = tokbf + (size_t)s * SN * DD + (size_t)r0 * DD;
    float a0 = 0.f, a1 = 0.f, a2 = 0.f;
#pragma unroll 4
    for (int n = 0; n < 96; ++n) {
      size_t ro = (size_t)n * DD;
      float v0 = p[ro + t];
      float v1 = p[ro + t + 256];
      float v2 = p[ro + t + 512];
      a0 += v0; a1 += v1; a2 += v2;
      q[ro + t] = f2bf(v0);
      q[ro + t + 256] = f2bf(v1);
      q[ro + t + 512] = f2bf(v2);
    }
    float* pp = partials + (size_t)slab * NB * DD + (size_t)s * DD;
    pp[t] = a0; pp[t + 256] = a1; pp[t + 512] = a2;
    if (blk == 0 && t < 16) out[O4 + t] = 0.f;
    return;
  }
  const float* src; u16* dst;
  int srcld, dstld, row_off, col_off, wrow_off, wcol_off;
  if (blk < 1056) {
    int i = blk - 768;             // W1
    int e = i / 36, rem = i % 36;
    int dt = rem / 3, rt = rem % 3;
    src = W1 + (size_t)e * DD * RR; srcld = RR;
    dst = W1T + (size_t)e * RR * DD; dstld = DD;
    row_off = dt * 64; col_off = rt * 64;
    wrow_off = rt * 64; wcol_off = dt * 64;
  } else {
    int i = blk - 1056;            // W2
    int e = i / 36, rem = i % 36;
    int rt = rem / 12, dt = rem % 12;
    src = W2 + (size_t)e * RR * DD; srcld = DD;
    dst = W2T + (size_t)e * DD * RR; dstld = RR;
    row_off = rt * 64; col_off = dt * 64;
    wrow_off = dt * 64; wcol_off = rt * 64;
  }
#pragma unroll
  for (int it = 0; it < 16; ++it) {
    int idx = t + 256 * it;
    int r = idx >> 6, c = idx & 63;
    tile[r][c] = src[(size_t)(row_off + r) * srcld + col_off + c];
  }
  __syncthreads();
#pragma unroll
  for (int it = 0; it < 8; ++it) {
    int idx = t + 256 * it;
    int r2 = idx >> 5, cp = idx & 31;
    u32 pack = (u32)f2bf(tile[2 * cp][r2]) | ((u32)f2bf(tile[2 * cp + 1][r2]) << 16);
    *(u32*)&dst[(size_t)(wrow_off + r2) * dstld + wcol_off + 2 * cp] = pack;
  }
}

// ---------------- kernel 2: gating (+ fused importance/load atomics) ----------------
__global__ void gate_kernel(const float* __restrict__ partials, const float* __restrict__ Wg,
                            const float* __restrict__ bg, float* __restrict__ out,
                            float* __restrict__ wsp, int* __restrict__ wse) {
  int b = blockIdx.x;
  int l = threadIdx.x;  // 64
  float acc[NE];
#pragma unroll
  for (int e = 0; e < NE; ++e) acc[e] = 0.f;
  for (int d = l; d < DD; d += 64) {
    float x = 0.f;
#pragma unroll
    for (int k = 0; k < 6; ++k) x += partials[(size_t)k * NB * DD + (size_t)b * DD + d];
    x *= (1.0f / 576.0f);
    const float* wrow = Wg + d * NE;
#pragma unroll
    for (int e = 0; e < NE; ++e) acc[e] += x * wrow[e];
  }
#pragma unroll
  for (int off = 32; off > 0; off >>= 1) {
#pragma unroll
    for (int e = 0; e < NE; ++e) acc[e] += __shfl_down(acc[e], off);
  }
  if (l == 0) {
    float lg[NE];
#pragma unroll
    for (int e = 0; e < NE; ++e) lg[e] = acc[e] + bg[e];
#pragma unroll
    for (int e = 0; e < NE; ++e) out[O1 + b * NE + e] = lg[e];
    float m = lg[0]; int bi = 0;
#pragma unroll
    for (int e = 1; e < NE; ++e) { if (lg[e] > m) { m = lg[e]; bi = e; } }
    float s = 0.f;
#pragma unroll
    for (int e = 0; e < NE; ++e) s += expf(lg[e] - m);
    float pv = 1.0f / s;
    out[O2 + b] = (float)bi;
#pragma unroll
    for (int e = 0; e < NE; ++e) out[O3 + b * NE + e] = (e == bi) ? pv : 0.f;
    wsp[b] = pv;
    wse[b] = bi;
    atomicAdd(&out[O4 + bi], pv);
    atomicAdd(&out[O5 + bi], 1.0f / 128.0f);
  }
}

// ---------------- kernel 3: fused bottleneck adapter (R5-proven core) ----------
// Block: 96 rows of one sample. Phase1: H=gelu(X@W1+b1), K=768, BK=64, dbuf, counted vmcnt.
// Phase2: out = p*(H@W2+b2), 6 chunks x 128 cols, K=192, W2 dbuf.
// LDS 73728B: p1: X0@0(12K) X1@12K W0@24K(24K) W1@48K | p2: Hs@0(36K) W2b0@36K(16K) W2b1@52K
__launch_bounds__(256, 2)
__global__ void adapter_kernel(const u16* __restrict__ tokbf, const u16* __restrict__ W1T,
                               const u16* __restrict__ W2T, const float* __restrict__ b1,
                               const float* __restrict__ b2, const float* __restrict__ wsp,
                               const int* __restrict__ wse, float* __restrict__ out) {
  __shared__ __align__(16) unsigned char smem[73728];

  int bid = blockIdx.x;
  int wg = (bid & 7) * 96 + (bid >> 3);   // chunked XCD swizzle (768 = 8*96, bijective)
  int b = wg / 6, tile6 = wg % 6;
  int row0 = tile6 * 96;
  int t = threadIdx.x;
  int l = t & 63;
  int w = t >> 6;
  int wr = w >> 1;
  int wc = w & 1;
  int lr = l & 15;
  int kg = l >> 4;

  int e = wse[b];
  float p = wsp[b];

  const u16* Xg = tokbf + (size_t)b * SN * DD + (size_t)row0 * DD;
  const u16* W1g = W1T + (size_t)e * RR * DD;
  const u16* W2g = W2T + (size_t)e * DD * RR;

  auto stage1 = [&](int kt, int buf) {
    u16* Xs = (u16*)(smem + buf * 12288);
    u16* Ws = (u16*)(smem + 24576 + buf * 24576);
    int kb = kt * 64;
#pragma unroll
    for (int i = 0; i < 3; ++i) {
      int idx = t + 256 * i;          // 0..767
      int row = idx >> 3, g = idx & 7;
      gload16(Xg + (size_t)row * DD + kb + ((g ^ (row & 7)) << 3), Xs + idx * 8);
    }
#pragma unroll
    for (int i = 0; i < 6; ++i) {
      int idx = t + 256 * i;          // 0..1535
      int r = idx >> 3, g = idx & 7;
      gload16(W1g + (size_t)r * DD + kb + ((g ^ (r & 7)) << 3), Ws + idx * 8);
    }
  };

  f32x4 acc1[3][6];
#pragma unroll
  for (int i = 0; i < 3; ++i)
#pragma unroll
    for (int j = 0; j < 6; ++j) acc1[i][j] = (f32x4){0.f, 0.f, 0.f, 0.f};

  // ---- phase 1: 12 K-steps BK=64, dbuf, 1-ahead, counted vmcnt ----
  stage1(0, 0);
  int cur = 0;
  for (int kt = 0; kt < 12; ++kt) {
    if (kt < 11) {
      stage1(kt + 1, cur ^ 1);
      asm volatile("s_waitcnt vmcnt(9)" ::: "memory");
    } else {
      asm volatile("s_waitcnt vmcnt(0)" ::: "memory");
    }
    __builtin_amdgcn_s_barrier();
    u16* Xs = (u16*)(smem + cur * 12288);
    u16* Ws = (u16*)(smem + 24576 + cur * 24576);
#pragma unroll
    for (int ks = 0; ks < 2; ++ks) {
      int q = ks * 4 + kg;
      bf16x8 a[3], bb[6];
#pragma unroll
      for (int i = 0; i < 3; ++i) {
        int row = wr * 48 + i * 16 + lr;
        a[i] = *(const bf16x8*)&Xs[row * 64 + ((q ^ (row & 7)) << 3)];
      }
#pragma unroll
      for (int j = 0; j < 6; ++j) {
        int c = wc * 96 + j * 16 + lr;
        bb[j] = *(const bf16x8*)&Ws[c * 64 + ((q ^ (c & 7)) << 3)];
      }
#pragma unroll
      for (int i = 0; i < 3; ++i)
#pragma unroll
        for (int j = 0; j < 6; ++j)
          acc1[i][j] = __builtin_amdgcn_mfma_f32_16x16x32_bf16(a[i], bb[j], acc1[i][j], 0, 0, 0);
    }
    asm volatile("" ::: "memory");
    __builtin_amdgcn_s_barrier();
    cur ^= 1;
  }

  auto stage2 = [&](int nc, int kt2, int buf) {
    u16* Wb = (u16*)(smem + 36864 + buf * 16384);
#pragma unroll
    for (int i = 0; i < 4; ++i) {
      int idx = t + 256 * i;          // 0..1023
      int c = idx >> 3, g = idx & 7;
      gload16(W2g + (size_t)(nc * 128 + c) * RR + kt2 * 64 + ((g ^ (c & 7)) << 3), Wb + idx * 8);
    }
  };
  stage2(0, 0, 0);  // lands during gelu epilogue

  // ---- epilogue 1: bias + gelu -> Hs (bf16, granule-swizzled, ld=192) ----
  u16* Hs = (u16*)smem;
#pragma unroll
  for (int j = 0; j < 6; ++j) {
    int col = wc * 96 + j * 16 + lr;
    float bv = b1[e * RR + col];
#pragma unroll
    for (int i = 0; i < 3; ++i) {
      int rbase = wr * 48 + i * 16 + kg * 4;
#pragma unroll
      for (int r2 = 0; r2 < 4; ++r2) {
        int row = rbase + r2;
        float x = acc1[i][j][r2] + bv;
        float x3 = x * (1.f + 0.044715f * x * x);
        float tt = 0.7978845608028654f * x3;
        float ex = __expf(2.f * tt);
        float th = 1.f - 2.f / (ex + 1.f);
        float h = 0.5f * x * (1.f + th);
        Hs[row * 192 + ((((col >> 3) ^ (row & 7)) << 3) | (col & 7))] = f2bf(h);
      }
    }
  }
  __syncthreads();

  // ---- phase 2: 6 chunks x 3 K-steps, W2 dbuf, counted vmcnt (stores in flight) ----
  for (int nc = 0; nc < 6; ++nc) {
    f32x4 acc2[3][4];
#pragma unroll
    for (int i = 0; i < 3; ++i)
#pragma unroll
      for (int j = 0; j < 4; ++j) acc2[i][j] = (f32x4){0.f, 0.f, 0.f, 0.f};

    for (int kt2 = 0; kt2 < 3; ++kt2) {
      int s = nc * 3 + kt2;
      if (s < 17) {
        int nc2 = (kt2 == 2) ? nc + 1 : nc;
        int kt2b = (kt2 == 2) ? 0 : kt2 + 1;
        stage2(nc2, kt2b, (s + 1) & 1);
      }
      if (s == 17)
        asm volatile("s_waitcnt vmcnt(0)" ::: "memory");
      else if (kt2 == 0 && s > 0)
        asm volatile("s_waitcnt vmcnt(52)" ::: "memory");  // 48 stores + 4 next-loads in flight
      else
        asm volatile("s_waitcnt vmcnt(4)" ::: "memory");
      __builtin_amdgcn_s_barrier();

      u16* Wb = (u16*)(smem + 36864 + (s & 1) * 16384);
#pragma unroll
      for (int ks = 0; ks < 2; ++ks) {
        int q2 = ks * 4 + kg;
        int q = kt2 * 8 + q2;
        bf16x8 a[3], bb[4];
#pragma unroll
        for (int i = 0; i < 3; ++i) {
          int row = wr * 48 + i * 16 + lr;
          a[i] = *(const bf16x8*)&Hs[row * 192 + ((q ^ (row & 7)) << 3)];
        }
#pragma unroll
        for (int j = 0; j < 4; ++j) {
          int c = wc * 64 + j * 16 + lr;
          bb[j] = *(const bf16x8*)&Wb[c * 64 + ((q2 ^ (c & 7)) << 3)];
        }
#pragma unroll
        for (int i = 0; i < 3; ++i)
#pragma unroll
          for (int j = 0; j < 4; ++j)
            acc2[i][j] = __builtin_amdgcn_mfma_f32_16x16x32_bf16(a[i], bb[j], acc2[i][j], 0, 0, 0);
      }
      if (kt2 == 2) {
#pragma unroll
        for (int j = 0; j < 4; ++j) {
          int colg = nc * 128 + wc * 64 + j * 16 + lr;
          float bv = b2[e * DD + colg];
#pragma unroll
          for (int i = 0; i < 3; ++i) {
            int rbase = row0 + wr * 48 + i * 16 + kg * 4;
#pragma unroll
            for (int r2 = 0; r2 < 4; ++r2) {
              out[(size_t)b * SN * DD + (size_t)(rbase + r2) * DD + colg] = p * (acc2[i][j][r2] + bv);
            }
          }
        }
      }
      asm volatile("" ::: "memory");
      __builtin_amdgcn_s_barrier();
    }
  }
}

extern "C" void kernel_launch(void* const* d_in, const int* in_sizes, int n_in,
                              void* d_out, int out_size, void* d_ws, size_t ws_size,
                              hipStream_t stream) {
  (void)in_sizes; (void)n_in; (void)out_size; (void)ws_size;
  const float* tok = (const float*)d_in[0];
  const float* Wg  = (const float*)d_in[1];
  const float* bg  = (const float*)d_in[2];
  const float* W1  = (const float*)d_in[3];
  const float* b1  = (const float*)d_in[4];
  const float* W2  = (const float*)d_in[5];
  const float* b2  = (const float*)d_in[6];
  float* out = (float*)d_out;

  char* w = (char*)d_ws;
  u16*  tokbf    = (u16*)w;                      // 113,246,208 B
  float* partials = (float*)(w + 113246208);     // 6*128*768*4 = 2,359,296 B
  float* wsp      = (float*)(w + 115605504);     // 512 B
  int*   wse      = (int*)(w + 115606016);       // 512 B
  u16*  W1T      = (u16*)(w + 115606528);        // 2,359,296 B
  u16*  W2T      = (u16*)(w + 117965824);        // 2,359,296 B (end ~120.3 MB)

  hipLaunchKernelGGL(prep_kernel, dim3(1344), dim3(256), 0, stream, tok, tokbf, partials, W1, W2, W1T, W2T, out);
  hipLaunchKernelGGL(gate_kernel, dim3(128), dim3(64), 0, stream, partials, Wg, bg, out, wsp, wse);
  hipLaunchKernelGGL(adapter_kernel, dim3(768), dim3(256), 0, stream, tokbf, W1T, W2T, b1, b2, wsp, wse, out);
}